// Round 1
// baseline (207.980 us; speedup 1.0000x reference)
//
#include <hip/hip_runtime.h>
#include <math.h>

#define NN 1000000
#define WD 20
#define NB1 3907          // ceil(NN/256)
#define NB7 977           // ceil(NN/1024)

// d_out layout (floats): out[325] | rw[NN] | ww[NN] | new_memory[NN*20] | nrh[20]
#define OUT_OFF 0
#define RW_OFF  325
#define WW_OFF  1000325
#define NM_OFF  2000325
#define NRH_OFF 22000325

__device__ __forceinline__ float sigmoidf_(float x){ return 1.0f/(1.0f+expf(-x)); }
__device__ __forceinline__ float softplusf_(float x){ return (x>30.f)?x:log1pf(expf(x)); }

// ---------------- K0: tiny controller MLP + head params -> P ----------------
// P layout (floats): kr:0-19 gr:20 sr:21-23 gammar:24 betar:25 knr:26
//                    kw:32-51 gw:52 sw:53-55 gammaw:56 betaw:57 knw:58
//                    erase:64-83 addraw:84-103 rho:104 ah0:105 ah1:106
//                    m_r:107 m_w:108 addf:112-131
__global__ void k_head(const float* __restrict__ X,
                       const float* __restrict__ W1, const float* __restrict__ b1,
                       const float* __restrict__ W2, const float* __restrict__ b2,
                       const float* __restrict__ Wxi, const float* __restrict__ bxi,
                       const float* __restrict__ Wz, const float* __restrict__ bz,
                       float* __restrict__ P){
  __shared__ float h1[48], h2[72], xi[92], zeta[3];
  int t = threadIdx.x;
  if(t<48){ float a=b1[t]; const float* w=W1+t*14; for(int c=0;c<14;c++) a+=X[c]*w[c]; h1[t]=a; }
  __syncthreads();
  if(t<72){ float a=b2[t]; const float* w=W2+t*48; for(int c=0;c<48;c++) a+=h1[c]*w[c]; h2[t]=a; }
  __syncthreads();
  if(t<92){ float a=bxi[t]; const float* w=Wxi+t*72; for(int c=0;c<72;c++) a+=h2[c]*w[c]; xi[t]=a; }
  else if(t<95){ int z=t-92; float a=bz[z]; const float* w=Wz+z*72; for(int c=0;c<72;c++) a+=h2[c]*w[c]; zeta[z]=a; }
  __syncthreads();
  if(t<20){
    P[0+t]  = tanhf(xi[t]);
    P[32+t] = tanhf(xi[26+t]);
    P[64+t] = sigmoidf_(xi[52+t]);
    P[84+t] = tanhf(xi[72+t]);
  }
  if(t==32){ // read head scalars, rp = xi[0..25]
    const float* p = xi;
    float g=sigmoidf_(p[20]);
    float a0=p[21],a1=p[22],a2=p[23];
    float mx=fmaxf(a0,fmaxf(a1,a2));
    float e0=expf(a0-mx),e1=expf(a1-mx),e2=expf(a2-mx),es=e0+e1+e2;
    float gamma=1.0f+softplusf_(p[24]);
    float beta=softplusf_(p[25]);
    float n2=0.f; for(int j=0;j<20;j++){ float ke=tanhf(p[j])+1e-16f; n2+=ke*ke; }
    P[20]=g; P[21]=e0/es; P[22]=e1/es; P[23]=e2/es; P[24]=gamma; P[25]=beta;
    P[26]=fmaxf(sqrtf(n2),1e-8f);
  }
  if(t==33){ // write head scalars, wp = xi[26..51]
    const float* p = xi+26;
    float g=sigmoidf_(p[20]);
    float a0=p[21],a1=p[22],a2=p[23];
    float mx=fmaxf(a0,fmaxf(a1,a2));
    float e0=expf(a0-mx),e1=expf(a1-mx),e2=expf(a2-mx),es=e0+e1+e2;
    float gamma=1.0f+softplusf_(p[24]);
    float beta=softplusf_(p[25]);
    float n2=0.f; for(int j=0;j<20;j++){ float ke=tanhf(p[j])+1e-16f; n2+=ke*ke; }
    P[52]=g; P[53]=e0/es; P[54]=e1/es; P[55]=e2/es; P[56]=gamma; P[57]=beta;
    P[58]=fmaxf(sqrtf(n2),1e-8f);
  }
  if(t==34){
    P[104]=sigmoidf_(zeta[0]);
    float mx=fmaxf(zeta[1],zeta[2]);
    float e1=expf(zeta[1]-mx), e2=expf(zeta[2]-mx);
    P[105]=e1/(e1+e2); P[106]=e2/(e1+e2);
  }
}

// ---------------- K1: cosine scores for both heads + block max ----------------
__global__ __launch_bounds__(256) void k_scores(const float* __restrict__ M, const float* __restrict__ P,
                         float* __restrict__ score_r, float* __restrict__ score_w,
                         float* __restrict__ pmax){
  int i = blockIdx.x*256 + threadIdx.x;
  float sr=-3.4e38f, sw=-3.4e38f;
  if(i<NN){
    float betar=P[25], betaw=P[57], knr=P[26], knw=P[58];
    const float4* row = (const float4*)(M + (size_t)i*WD);
    float dr=0.f,dw=0.f,n2=0.f;
#pragma unroll
    for(int q=0;q<5;q++){
      float4 v=row[q];
      float m0=v.x+1e-16f, m1=v.y+1e-16f, m2=v.z+1e-16f, m3=v.w+1e-16f;
      dr += m0*(P[4*q+0]+1e-16f)+m1*(P[4*q+1]+1e-16f)+m2*(P[4*q+2]+1e-16f)+m3*(P[4*q+3]+1e-16f);
      dw += m0*(P[32+4*q+0]+1e-16f)+m1*(P[32+4*q+1]+1e-16f)+m2*(P[32+4*q+2]+1e-16f)+m3*(P[32+4*q+3]+1e-16f);
      n2 += m0*m0+m1*m1+m2*m2+m3*m3;
    }
    float nm = fmaxf(sqrtf(n2),1e-8f);
    sr = betar*(dr/(nm*knr));
    sw = betaw*(dw/(nm*knw));
    score_r[i]=sr; score_w[i]=sw;
  }
  __shared__ float r1[256], r2[256];
  r1[threadIdx.x]=sr; r2[threadIdx.x]=sw; __syncthreads();
  for(int o=128;o>0;o>>=1){
    if(threadIdx.x<o){ r1[threadIdx.x]=fmaxf(r1[threadIdx.x],r1[threadIdx.x+o]);
                       r2[threadIdx.x]=fmaxf(r2[threadIdx.x],r2[threadIdx.x+o]); }
    __syncthreads();
  }
  if(threadIdx.x==0){ pmax[2*blockIdx.x]=r1[0]; pmax[2*blockIdx.x+1]=r2[0]; }
}

// ---------------- K2: reduce block maxes -> P[107],P[108] ----------------
__global__ void k_redmax(const float* __restrict__ pmax, float* __restrict__ P, int nb){
  __shared__ float r1[256], r2[256];
  int t=threadIdx.x; float a=-3.4e38f,b=-3.4e38f;
  for(int x=t;x<nb;x+=256){ a=fmaxf(a,pmax[2*x]); b=fmaxf(b,pmax[2*x+1]); }
  r1[t]=a; r2[t]=b; __syncthreads();
  for(int o=128;o>0;o>>=1){ if(t<o){ r1[t]=fmaxf(r1[t],r1[t+o]); r2[t]=fmaxf(r2[t],r2[t+o]); } __syncthreads(); }
  if(t==0){ P[107]=r1[0]; P[108]=r2[0]; }
}

// ---------------- K3: exp-sum partials ----------------
__global__ __launch_bounds__(256) void k_expsum(const float* __restrict__ score_r, const float* __restrict__ score_w,
                         const float* __restrict__ P, double* __restrict__ psum){
  int i = blockIdx.x*256 + threadIdx.x;
  double er=0.0, ew=0.0;
  if(i<NN){ er=(double)expf(score_r[i]-P[107]); ew=(double)expf(score_w[i]-P[108]); }
  __shared__ double d1[256], d2[256];
  int t=threadIdx.x;
  d1[t]=er; d2[t]=ew; __syncthreads();
  for(int o=128;o>0;o>>=1){ if(t<o){ d1[t]+=d1[t+o]; d2[t]+=d2[t+o]; } __syncthreads(); }
  if(t==0){ psum[2*blockIdx.x]=d1[0]; psum[2*blockIdx.x+1]=d2[0]; }
}

// ---------------- generic pair double reduce ----------------
__global__ void k_redsum(const double* __restrict__ part, double* __restrict__ outp, int nb){
  __shared__ double d1[256], d2[256];
  int t=threadIdx.x; double a=0.0,b=0.0;
  for(int x=t;x<nb;x+=256){ a+=part[2*x]; b+=part[2*x+1]; }
  d1[t]=a; d2[t]=b; __syncthreads();
  for(int o=128;o>0;o>>=1){ if(t<o){ d1[t]+=d1[t+o]; d2[t]+=d2[t+o]; } __syncthreads(); }
  if(t==0){ outp[0]=d1[0]; outp[1]=d2[0]; }
}

// ---------------- K5: interpolate + circular shift + pow, Z partials ----------------
__global__ __launch_bounds__(256) void k_shiftpow(const float* __restrict__ score_r, const float* __restrict__ score_w,
                           const float* __restrict__ wpr, const float* __restrict__ wpw,
                           const float* __restrict__ P, const double* __restrict__ Sd,
                           float* __restrict__ w_r, float* __restrict__ w_w,
                           double* __restrict__ pZ){
  int i = blockIdx.x*256 + threadIdx.x;
  double zr=0.0, zw=0.0;
  if(i<NN){
    int im1 = (i==0)?(NN-1):(i-1);
    int ip1 = (i==NN-1)?0:(i+1);
    float mr=P[107], Srf=(float)Sd[0], gr=P[20], omgr=1.0f-P[20];
    float mw=P[108], Swf=(float)Sd[1], gw=P[52], omgw=1.0f-P[52];
    float wg_rm = gr*(expf(score_r[im1]-mr)/Srf) + omgr*wpr[im1];
    float wg_r0 = gr*(expf(score_r[i  ]-mr)/Srf) + omgr*wpr[i  ];
    float wg_rp = gr*(expf(score_r[ip1]-mr)/Srf) + omgr*wpr[ip1];
    float wg_wm = gw*(expf(score_w[im1]-mw)/Swf) + omgw*wpw[im1];
    float wg_w0 = gw*(expf(score_w[i  ]-mw)/Swf) + omgw*wpw[i  ];
    float wg_wp = gw*(expf(score_w[ip1]-mw)/Swf) + omgw*wpw[ip1];
    float wrv = powf(P[21]*wg_rm + P[22]*wg_r0 + P[23]*wg_rp, P[24]);
    float wwv = powf(P[53]*wg_wm + P[54]*wg_w0 + P[55]*wg_wp, P[56]);
    w_r[i]=wrv; w_w[i]=wwv; zr=(double)wrv; zw=(double)wwv;
  }
  __shared__ double d1[256], d2[256];
  int t=threadIdx.x;
  d1[t]=zr; d2[t]=zw; __syncthreads();
  for(int o=128;o>0;o>>=1){ if(t<o){ d1[t]+=d1[t+o]; d2[t]+=d2[t+o]; } __syncthreads(); }
  if(t==0){ pZ[2*blockIdx.x]=d1[0]; pZ[2*blockIdx.x+1]=d2[0]; }
}

// ---------------- K7: normalize -> rw,ww; fused rw@Memory partials ----------------
__global__ __launch_bounds__(1024) void k_wfin(const float* __restrict__ M,
                        const float* __restrict__ w_r, const float* __restrict__ w_w,
                        const double* __restrict__ Sd,
                        float* __restrict__ rw_out, float* __restrict__ ww_out,
                        double* __restrict__ pnrh){
  int i = blockIdx.x*1024 + threadIdx.x;
  float acc[20];
#pragma unroll
  for(int j=0;j<20;j++) acc[j]=0.f;
  if(i<NN){
    float zr=(float)(Sd[2]+1e-16), zw=(float)(Sd[3]+1e-16);
    float rwv = w_r[i]/zr;
    float wwv = w_w[i]/zw;
    rw_out[i]=rwv; ww_out[i]=wwv;
    const float4* row=(const float4*)(M+(size_t)i*WD);
#pragma unroll
    for(int q=0;q<5;q++){
      float4 v=row[q];
      acc[4*q+0]=rwv*v.x; acc[4*q+1]=rwv*v.y; acc[4*q+2]=rwv*v.z; acc[4*q+3]=rwv*v.w;
    }
  }
#pragma unroll
  for(int j=0;j<20;j++){
    for(int off=32;off>0;off>>=1) acc[j]+=__shfl_down(acc[j],off,64);
  }
  __shared__ float wsum[16][20];
  int wave=threadIdx.x>>6, lane=threadIdx.x&63;
  if(lane==0){
#pragma unroll
    for(int j=0;j<20;j++) wsum[wave][j]=acc[j];
  }
  __syncthreads();
  if(threadIdx.x<20){
    double s=0.0;
    for(int w=0;w<16;w++) s+=(double)wsum[w][threadIdx.x];
    pnrh[(size_t)blockIdx.x*20+threadIdx.x]=s;
  }
}

// ---------------- helper: one 4-layer ALU net ----------------
__device__ void run_net(int t, const float* in, float* bufA, float* bufB, float* outv,
                        float* red, float* mS,
                        const float* __restrict__ W1,const float* __restrict__ b1,
                        const float* __restrict__ W2,const float* __restrict__ b2,
                        const float* __restrict__ W3,const float* __restrict__ b3,
                        const float* __restrict__ W4,const float* __restrict__ b4,
                        float headw){
  if(t<110){ float a=b1[t]; const float* w=W1+t*40;  for(int c=0;c<40;c++)  a+=in[c]*w[c];   bufA[t]=fmaxf(a,0.f); }
  __syncthreads();
  if(t<190){ float a=b2[t]; const float* w=W2+t*110; for(int c=0;c<110;c++) a+=bufA[c]*w[c]; bufB[t]=fmaxf(a,0.f); }
  __syncthreads();
  if(t<270){ float a=b3[t]; const float* w=W3+t*190; for(int c=0;c<190;c++) a+=bufB[c]*w[c]; bufA[t]=fmaxf(a,0.f); }
  __syncthreads();
  float lt=-3.0e38f;
  if(t<325){ float a=b4[t]; const float* w=W4+t*270; for(int c=0;c<270;c++) a+=bufA[c]*w[c]; lt=a; }
  red[t]=lt; __syncthreads();
  for(int o=256;o>0;o>>=1){ if(t<o) red[t]=fmaxf(red[t],red[t+o]); __syncthreads(); }
  if(t==0) mS[0]=red[0]; __syncthreads();
  float e=(t<325)?expf(lt-mS[0]):0.f;
  red[t]=e; __syncthreads();
  for(int o=256;o>0;o>>=1){ if(t<o) red[t]+=red[t+o]; __syncthreads(); }
  if(t==0) mS[1]=red[0]; __syncthreads();
  if(t<325) outv[t]+=headw*(e/mS[1]);
  __syncthreads();
}

// ---------------- K8: reduce nrh, ALU MLPs, v, add_final ----------------
__global__ __launch_bounds__(512) void k_alu(const float* __restrict__ read_head,
                      const float* __restrict__ Wv, const float* __restrict__ bv,
                      const float* __restrict__ aW1,const float* __restrict__ ab1,
                      const float* __restrict__ aW2,const float* __restrict__ ab2,
                      const float* __restrict__ aW3,const float* __restrict__ ab3,
                      const float* __restrict__ aW4,const float* __restrict__ ab4,
                      const float* __restrict__ mW1,const float* __restrict__ mb1,
                      const float* __restrict__ mW2,const float* __restrict__ mb2,
                      const float* __restrict__ mW3,const float* __restrict__ mb3,
                      const float* __restrict__ mW4,const float* __restrict__ mb4,
                      const double* __restrict__ pnrh, int nb7,
                      float* __restrict__ P, float* __restrict__ out){
  __shared__ float in[40], bufA[325], bufB[325], outv[325], red[512], mS[2];
  __shared__ double dred[320];
  int t=threadIdx.x;
  if(t<320){
    int g=t/20, j=t%20;
    double s=0.0;
    for(int b=g;b<nb7;b+=16) s+=pnrh[(size_t)b*20+j];
    dred[t]=s;
  }
  __syncthreads();
  if(t<20){
    double s=0.0;
    for(int g=0;g<16;g++) s+=dred[g*20+t];
    float f=(float)s;
    out[NRH_OFF+t]=f;
    in[20+t]=f;
    in[t]=read_head[t];
  }
  if(t<325) outv[t]=0.f;
  __syncthreads();
  run_net(t,in,bufA,bufB,outv,red,mS,aW1,ab1,aW2,ab2,aW3,ab3,aW4,ab4,P[105]);
  run_net(t,in,bufA,bufB,outv,red,mS,mW1,mb1,mW2,mb2,mW3,mb3,mW4,mb4,P[106]);
  if(t<325) out[OUT_OFF+t]=outv[t];
  if(t<20){
    float a=bv[t]; const float* w=Wv+t*325;
    for(int c=0;c<325;c++) a+=outv[c]*w[c];
    float rho=P[104];
    P[112+t]=rho*P[84+t]+(1.0f-rho)*a;
  }
}

// ---------------- K9: new_memory = M*(1-ww^T erase) + ww^T add ----------------
__global__ __launch_bounds__(256) void k_memupd(const float* __restrict__ M, const float* __restrict__ ww,
                         const float* __restrict__ P, float* __restrict__ nm){
  int i = blockIdx.x*256 + threadIdx.x;
  if(i>=NN) return;
  float er[20], af[20];
#pragma unroll
  for(int j=0;j<20;j++){ er[j]=P[64+j]; af[j]=P[112+j]; }
  float w=ww[i];
  const float4* row=(const float4*)(M+(size_t)i*WD);
  float* dst = nm + (size_t)i*WD;
#pragma unroll
  for(int q=0;q<5;q++){
    float4 v=row[q];
    dst[4*q+0]=v.x*(1.0f-w*er[4*q+0])+w*af[4*q+0];
    dst[4*q+1]=v.y*(1.0f-w*er[4*q+1])+w*af[4*q+1];
    dst[4*q+2]=v.z*(1.0f-w*er[4*q+2])+w*af[4*q+2];
    dst[4*q+3]=v.w*(1.0f-w*er[4*q+3])+w*af[4*q+3];
  }
}

extern "C" void kernel_launch(void* const* d_in, const int* in_sizes, int n_in,
                              void* d_out, int out_size, void* d_ws, size_t ws_size,
                              hipStream_t stream) {
  const float* X    =(const float*)d_in[0];
  const float* rwp  =(const float*)d_in[1];   // read_weights (prev)
  const float* wwp  =(const float*)d_in[2];   // write_weights (prev)
  const float* Mem  =(const float*)d_in[3];
  const float* rhd  =(const float*)d_in[4];   // read_head
  const float* W1   =(const float*)d_in[5];
  const float* b1   =(const float*)d_in[6];
  const float* W2   =(const float*)d_in[7];
  const float* b2   =(const float*)d_in[8];
  const float* Wxi  =(const float*)d_in[9];
  const float* bxi  =(const float*)d_in[10];
  const float* Wz   =(const float*)d_in[11];
  const float* bz   =(const float*)d_in[12];
  const float* Wv   =(const float*)d_in[13];
  const float* bv   =(const float*)d_in[14];
  const float* aW1  =(const float*)d_in[15];
  const float* ab1  =(const float*)d_in[16];
  const float* aW2  =(const float*)d_in[17];
  const float* ab2  =(const float*)d_in[18];
  const float* aW3  =(const float*)d_in[19];
  const float* ab3  =(const float*)d_in[20];
  const float* aW4  =(const float*)d_in[21];
  const float* ab4  =(const float*)d_in[22];
  const float* mW1  =(const float*)d_in[23];
  const float* mb1  =(const float*)d_in[24];
  const float* mW2  =(const float*)d_in[25];
  const float* mb2  =(const float*)d_in[26];
  const float* mW3  =(const float*)d_in[27];
  const float* mb3  =(const float*)d_in[28];
  const float* mW4  =(const float*)d_in[29];
  const float* mb4  =(const float*)d_in[30];

  float* out = (float*)d_out;
  float*  P    = (float*) d_ws;
  float*  pmax = (float*) ((char*)d_ws + 4096);
  double* psum = (double*)((char*)d_ws + 65536);
  double* pZ   = (double*)((char*)d_ws + 131072);
  double* pnrh = (double*)((char*)d_ws + 196608);
  double* Sd   = (double*)((char*)d_ws + 851968);  // [0]=S_r [1]=S_w [2]=Z_r [3]=Z_w

  // stage big scratch in the (not-yet-written) new_memory region of d_out
  float* score_r = out + NM_OFF;
  float* score_w = score_r + NN;
  float* w_r     = score_w + NN;
  float* w_w     = w_r + NN;
  float* rw_out  = out + RW_OFF;
  float* ww_out  = out + WW_OFF;
  float* nm      = out + NM_OFF;

  k_head<<<1,128,0,stream>>>(X,W1,b1,W2,b2,Wxi,bxi,Wz,bz,P);
  k_scores<<<NB1,256,0,stream>>>(Mem,P,score_r,score_w,pmax);
  k_redmax<<<1,256,0,stream>>>(pmax,P,NB1);
  k_expsum<<<NB1,256,0,stream>>>(score_r,score_w,P,psum);
  k_redsum<<<1,256,0,stream>>>(psum,Sd,NB1);
  k_shiftpow<<<NB1,256,0,stream>>>(score_r,score_w,rwp,wwp,P,Sd,w_r,w_w,pZ);
  k_redsum<<<1,256,0,stream>>>(pZ,Sd+2,NB1);
  k_wfin<<<NB7,1024,0,stream>>>(Mem,w_r,w_w,Sd,rw_out,ww_out,pnrh);
  k_alu<<<1,512,0,stream>>>(rhd,Wv,bv,aW1,ab1,aW2,ab2,aW3,ab3,aW4,ab4,
                            mW1,mb1,mW2,mb2,mW3,mb3,mW4,mb4,pnrh,NB7,P,out);
  k_memupd<<<NB1,256,0,stream>>>(Mem,ww_out,P,nm);
}

// Round 2
// 120.460 us; speedup vs baseline: 1.7265x; 1.7265x over previous
//
#include <hip/hip_runtime.h>
#include <math.h>

#define NN 1000000
#define WD 20
#define NB 977            // blocks of 1024 rows (4 passes x 256 threads)
#define PST 1024          // pnrhT column stride

// d_out layout (floats): out[325] | rw[NN] | ww[NN] | new_memory[NN*20] | nrh[20]
#define OUT_OFF 0
#define RW_OFF  325
#define WW_OFF  1000325
#define NM_OFF  2000325
#define NRH_OFF 22000325

__device__ __forceinline__ float sigmoidf_(float x){ return 1.0f/(1.0f+expf(-x)); }
__device__ __forceinline__ float softplusf_(float x){ return (x>30.f)?x:log1pf(expf(x)); }

// ---------------- K0: tiny controller MLP + head params -> P ----------------
// P: kr:0-19 gr:20 sr:21-23 gammar:24 betar:25 knr:26
//    kw:32-51 gw:52 sw:53-55 gammaw:56 betaw:57 knw:58
//    erase:64-83 addraw:84-103 rho:104 ah0:105 ah1:106 addf:112-131
__global__ void k_head(const float* __restrict__ X,
                       const float* __restrict__ W1, const float* __restrict__ b1,
                       const float* __restrict__ W2, const float* __restrict__ b2,
                       const float* __restrict__ Wxi, const float* __restrict__ bxi,
                       const float* __restrict__ Wz, const float* __restrict__ bz,
                       float* __restrict__ P){
  __shared__ float h1[48], h2[72], xi[92], zeta[3];
  int t = threadIdx.x;
  if(t<48){ float a=b1[t]; const float* w=W1+t*14; for(int c=0;c<14;c++) a+=X[c]*w[c]; h1[t]=a; }
  __syncthreads();
  if(t<72){ float a=b2[t]; const float* w=W2+t*48; for(int c=0;c<48;c++) a+=h1[c]*w[c]; h2[t]=a; }
  __syncthreads();
  if(t<92){ float a=bxi[t]; const float* w=Wxi+t*72; for(int c=0;c<72;c++) a+=h2[c]*w[c]; xi[t]=a; }
  else if(t<95){ int z=t-92; float a=bz[z]; const float* w=Wz+z*72; for(int c=0;c<72;c++) a+=h2[c]*w[c]; zeta[z]=a; }
  __syncthreads();
  if(t<20){
    P[0+t]  = tanhf(xi[t]);
    P[32+t] = tanhf(xi[26+t]);
    P[64+t] = sigmoidf_(xi[52+t]);
    P[84+t] = tanhf(xi[72+t]);
  }
  if(t==32){
    const float* p = xi;
    float g=sigmoidf_(p[20]);
    float a0=p[21],a1=p[22],a2=p[23];
    float mx=fmaxf(a0,fmaxf(a1,a2));
    float e0=expf(a0-mx),e1=expf(a1-mx),e2=expf(a2-mx),es=e0+e1+e2;
    float gamma=1.0f+softplusf_(p[24]);
    float beta=softplusf_(p[25]);
    float n2=0.f; for(int j=0;j<20;j++){ float ke=tanhf(p[j])+1e-16f; n2+=ke*ke; }
    P[20]=g; P[21]=e0/es; P[22]=e1/es; P[23]=e2/es; P[24]=gamma; P[25]=beta;
    P[26]=fmaxf(sqrtf(n2),1e-8f);
  }
  if(t==33){
    const float* p = xi+26;
    float g=sigmoidf_(p[20]);
    float a0=p[21],a1=p[22],a2=p[23];
    float mx=fmaxf(a0,fmaxf(a1,a2));
    float e0=expf(a0-mx),e1=expf(a1-mx),e2=expf(a2-mx),es=e0+e1+e2;
    float gamma=1.0f+softplusf_(p[24]);
    float beta=softplusf_(p[25]);
    float n2=0.f; for(int j=0;j<20;j++){ float ke=tanhf(p[j])+1e-16f; n2+=ke*ke; }
    P[52]=g; P[53]=e0/es; P[54]=e1/es; P[55]=e2/es; P[56]=gamma; P[57]=beta;
    P[58]=fmaxf(sqrtf(n2),1e-8f);
  }
  if(t==34){
    P[104]=sigmoidf_(zeta[0]);
    float mx=fmaxf(zeta[1],zeta[2]);
    float e1=expf(zeta[1]-mx), e2=expf(zeta[2]-mx);
    P[105]=e1/(e1+e2); P[106]=e2/(e1+e2);
  }
}

// ------- K1: cosine scores + per-block {max, local expsum} partials -------
__global__ __launch_bounds__(256) void k_scores(const float* __restrict__ M, const float* __restrict__ P,
                         float* __restrict__ score_r, float* __restrict__ score_w,
                         float4* __restrict__ pms){
  int t=threadIdx.x, b=blockIdx.x;
  float kr[20], kw[20];
#pragma unroll
  for(int j=0;j<20;j++){ kr[j]=P[j]+1e-16f; kw[j]=P[32+j]+1e-16f; }
  float betar=P[25], betaw=P[57], knr=P[26], knw=P[58];
  float sR[4], sW[4];
#pragma unroll
  for(int p=0;p<4;p++){
    int i=b*1024+p*256+t;
    if(i<NN){
      const float4* row=(const float4*)(M+(size_t)i*WD);
      float dr=0.f,dw=0.f,n2=0.f;
#pragma unroll
      for(int q=0;q<5;q++){
        float4 v=row[q];
        float m0=v.x+1e-16f,m1=v.y+1e-16f,m2=v.z+1e-16f,m3=v.w+1e-16f;
        dr+=m0*kr[4*q]+m1*kr[4*q+1]+m2*kr[4*q+2]+m3*kr[4*q+3];
        dw+=m0*kw[4*q]+m1*kw[4*q+1]+m2*kw[4*q+2]+m3*kw[4*q+3];
        n2+=m0*m0+m1*m1+m2*m2+m3*m3;
      }
      float nm=fmaxf(sqrtf(n2),1e-8f);
      sR[p]=betar*(dr/(nm*knr));
      sW[p]=betaw*(dw/(nm*knw));
      score_r[i]=sR[p]; score_w[i]=sW[p];
    } else { sR[p]=-3.0e38f; sW[p]=-3.0e38f; }
  }
  __shared__ float r1[256], r2[256];
  __shared__ double d1[256], d2[256];
  float lm1=fmaxf(fmaxf(sR[0],sR[1]),fmaxf(sR[2],sR[3]));
  float lm2=fmaxf(fmaxf(sW[0],sW[1]),fmaxf(sW[2],sW[3]));
  r1[t]=lm1; r2[t]=lm2; __syncthreads();
  for(int o=128;o>0;o>>=1){ if(t<o){ r1[t]=fmaxf(r1[t],r1[t+o]); r2[t]=fmaxf(r2[t],r2[t+o]); } __syncthreads(); }
  float mb1=r1[0], mb2=r2[0]; __syncthreads();
  double s1=0.0,s2=0.0;
#pragma unroll
  for(int p=0;p<4;p++){ s1+=(double)expf(sR[p]-mb1); s2+=(double)expf(sW[p]-mb2); }
  d1[t]=s1; d2[t]=s2; __syncthreads();
  for(int o=128;o>0;o>>=1){ if(t<o){ d1[t]+=d1[t+o]; d2[t]+=d2[t+o]; } __syncthreads(); }
  if(t==0) pms[b]=make_float4(mb1,mb2,(float)d1[0],(float)d2[0]);
}

// ------- K2: interpolate+shift+pow; Z partials; fused unnormalized rw@M -------
__global__ __launch_bounds__(256) void k_shift(const float* __restrict__ score_r, const float* __restrict__ score_w,
                        const float* __restrict__ wpr, const float* __restrict__ wpw,
                        const float* __restrict__ M, const float* __restrict__ P,
                        const float4* __restrict__ pms,
                        float* __restrict__ w_r_out, float* __restrict__ w_w_out,
                        double* __restrict__ pZ, double* __restrict__ pnrhT){
  __shared__ float r1[256], r2[256];
  __shared__ double d1[256], d2[256];
  __shared__ float bmS[4];
  __shared__ float wsum[4][20];
  int t=threadIdx.x, b=blockIdx.x;
  // redundant global (m,S) reduction over NB partials
  float4 v[4];
#pragma unroll
  for(int k=0;k<4;k++){
    int idx=t+k*256;
    v[k] = (idx<NB) ? pms[idx] : make_float4(-3.0e38f,-3.0e38f,0.f,0.f);
  }
  float lm1=fmaxf(fmaxf(v[0].x,v[1].x),fmaxf(v[2].x,v[3].x));
  float lm2=fmaxf(fmaxf(v[0].y,v[1].y),fmaxf(v[2].y,v[3].y));
  r1[t]=lm1; r2[t]=lm2; __syncthreads();
  for(int o=128;o>0;o>>=1){ if(t<o){ r1[t]=fmaxf(r1[t],r1[t+o]); r2[t]=fmaxf(r2[t],r2[t+o]); } __syncthreads(); }
  if(t==0){ bmS[0]=r1[0]; bmS[1]=r2[0]; } __syncthreads();
  float mr=bmS[0], mw=bmS[1];
  double s1=0.0,s2=0.0;
#pragma unroll
  for(int k=0;k<4;k++){
    s1 += (double)v[k].z * (double)expf(v[k].x-mr);
    s2 += (double)v[k].w * (double)expf(v[k].y-mw);
  }
  d1[t]=s1; d2[t]=s2; __syncthreads();
  for(int o=128;o>0;o>>=1){ if(t<o){ d1[t]+=d1[t+o]; d2[t]+=d2[t+o]; } __syncthreads(); }
  if(t==0){ bmS[2]=(float)d1[0]; bmS[3]=(float)d2[0]; } __syncthreads();
  float Sr=bmS[2], Sw=bmS[3];
  float gr=P[20], s0r=P[21], s1r=P[22], s2r=P[23], gar=P[24];
  float gw=P[52], s0w=P[53], s1w=P[54], s2w=P[55], gaw=P[56];
  float omgr=1.0f-gr, omgw=1.0f-gw;
  float acc[20];
#pragma unroll
  for(int j=0;j<20;j++) acc[j]=0.f;
  double zr=0.0, zw=0.0;
  for(int p=0;p<4;p++){
    int i=b*1024+p*256+t;
    if(i<NN){
      int im1=(i==0)?(NN-1):(i-1);
      int ip1=(i==NN-1)?0:(i+1);
      float wgrm = gr*(expf(score_r[im1]-mr)/Sr) + omgr*wpr[im1];
      float wgr0 = gr*(expf(score_r[i  ]-mr)/Sr) + omgr*wpr[i  ];
      float wgrp = gr*(expf(score_r[ip1]-mr)/Sr) + omgr*wpr[ip1];
      float wgwm = gw*(expf(score_w[im1]-mw)/Sw) + omgw*wpw[im1];
      float wgw0 = gw*(expf(score_w[i  ]-mw)/Sw) + omgw*wpw[i  ];
      float wgwp = gw*(expf(score_w[ip1]-mw)/Sw) + omgw*wpw[ip1];
      float wr = powf(s0r*wgrm + s1r*wgr0 + s2r*wgrp, gar);
      float ww = powf(s0w*wgwm + s1w*wgw0 + s2w*wgwp, gaw);
      w_r_out[i]=wr; w_w_out[i]=ww;
      zr+=(double)wr; zw+=(double)ww;
      const float4* row=(const float4*)(M+(size_t)i*WD);
#pragma unroll
      for(int q=0;q<5;q++){
        float4 mv=row[q];
        acc[4*q+0]+=wr*mv.x; acc[4*q+1]+=wr*mv.y; acc[4*q+2]+=wr*mv.z; acc[4*q+3]+=wr*mv.w;
      }
    }
  }
  d1[t]=zr; d2[t]=zw; __syncthreads();
  for(int o=128;o>0;o>>=1){ if(t<o){ d1[t]+=d1[t+o]; d2[t]+=d2[t+o]; } __syncthreads(); }
  if(t==0){ pZ[2*b]=d1[0]; pZ[2*b+1]=d2[0]; }
#pragma unroll
  for(int j=0;j<20;j++){
    for(int off=32;off>0;off>>=1) acc[j]+=__shfl_down(acc[j],off,64);
  }
  int wave=t>>6, lane=t&63;
  if(lane==0){
#pragma unroll
    for(int j=0;j<20;j++) wsum[wave][j]=acc[j];
  }
  __syncthreads();
  if(t<20){
    double s=(double)wsum[0][t]+(double)wsum[1][t]+(double)wsum[2][t]+(double)wsum[3][t];
    pnrhT[(size_t)t*PST+b]=s;
  }
}

// ------- K3: Z reduce (redundant) + nrh column reduce; builds in40 -------
__global__ __launch_bounds__(256) void k_nrh(const double* __restrict__ pZ, const double* __restrict__ pnrhT,
                      const float* __restrict__ read_head,
                      float* __restrict__ in40, float* __restrict__ out, double* __restrict__ Sd){
  __shared__ double dd[256];
  __shared__ double bZ[2];
  int t=threadIdx.x, j=blockIdx.x;
  double a=0.0,c=0.0;
  for(int idx=t; idx<NB; idx+=256){ a+=pZ[2*idx]; c+=pZ[2*idx+1]; }
  dd[t]=a; __syncthreads();
  for(int o=128;o>0;o>>=1){ if(t<o) dd[t]+=dd[t+o]; __syncthreads(); }
  if(t==0) bZ[0]=dd[0]; __syncthreads();
  dd[t]=c; __syncthreads();
  for(int o=128;o>0;o>>=1){ if(t<o) dd[t]+=dd[t+o]; __syncthreads(); }
  if(t==0) bZ[1]=dd[0]; __syncthreads();
  if(j==0 && t==0){ Sd[0]=bZ[0]; Sd[1]=bZ[1]; }
  double s=0.0;
  for(int idx=t; idx<NB; idx+=256) s+=pnrhT[(size_t)j*PST+idx];
  dd[t]=s; __syncthreads();
  for(int o=128;o>0;o>>=1){ if(t<o) dd[t]+=dd[t+o]; __syncthreads(); }
  if(t==0){
    float nv=(float)(dd[0]/(bZ[0]+1e-16));
    in40[20+j]=nv; out[NRH_OFF+j]=nv;
    in40[j]=read_head[j];
  }
}

// ------- generic MLP layer: wave-per-row, both nets via grid halves -------
__global__ __launch_bounds__(256) void k_layer(const float* __restrict__ Wa, const float* __restrict__ ba,
                        const float* __restrict__ Wm, const float* __restrict__ bm,
                        const float* __restrict__ inA, const float* __restrict__ inM,
                        float* __restrict__ oA, float* __restrict__ oM,
                        int rows, int K, int RB, int doRelu){
  int net = (blockIdx.x >= RB) ? 1 : 0;
  const float* W = net ? Wm : Wa;
  const float* bb = net ? bm : ba;
  const float* in = net ? inM : inA;
  float* o = net ? oM : oA;
  int wave=threadIdx.x>>6, lane=threadIdx.x&63;
  int r=(blockIdx.x - net*RB)*4 + wave;
  if(r>=rows) return;
  const float* w = W + (size_t)r*K;
  float a=0.f;
  for(int c=lane; c<K; c+=64) a += w[c]*in[c];
  for(int off=32;off>0;off>>=1) a += __shfl_down(a,off,64);
  if(lane==0){
    float vv=a+bb[r];
    o[r]= doRelu ? fmaxf(vv,0.f) : vv;
  }
}

// ------- K8: softmax both nets, combine, out, v, add_final -------
__global__ __launch_bounds__(512) void k_fin(const float* __restrict__ h4a, const float* __restrict__ h4m,
                      const float* __restrict__ Wv, const float* __restrict__ bv,
                      float* __restrict__ P, float* __restrict__ out){
  __shared__ float red[512];
  __shared__ float A[325], B[325];
  __shared__ float sc[2];
  int t=threadIdx.x;
  // softmax net A
  float la=(t<325)?h4a[t]:-3.0e38f;
  red[t]=la; __syncthreads();
  for(int o=256;o>0;o>>=1){ if(t<o) red[t]=fmaxf(red[t],red[t+o]); __syncthreads(); }
  if(t==0) sc[0]=red[0]; __syncthreads();
  float ea=(t<325)?expf(la-sc[0]):0.f;
  red[t]=ea; __syncthreads();
  for(int o=256;o>0;o>>=1){ if(t<o) red[t]+=red[t+o]; __syncthreads(); }
  if(t==0) sc[1]=red[0]; __syncthreads();
  if(t<325) A[t]=ea/sc[1];
  __syncthreads();
  // softmax net M
  float lm=(t<325)?h4m[t]:-3.0e38f;
  red[t]=lm; __syncthreads();
  for(int o=256;o>0;o>>=1){ if(t<o) red[t]=fmaxf(red[t],red[t+o]); __syncthreads(); }
  if(t==0) sc[0]=red[0]; __syncthreads();
  float em=(t<325)?expf(lm-sc[0]):0.f;
  red[t]=em; __syncthreads();
  for(int o=256;o>0;o>>=1){ if(t<o) red[t]+=red[t+o]; __syncthreads(); }
  if(t==0) sc[1]=red[0]; __syncthreads();
  if(t<325) B[t]=em/sc[1];
  __syncthreads();
  float ah0=P[105], ah1=P[106];
  if(t<325){ float ov=ah0*A[t]+ah1*B[t]; out[OUT_OFF+t]=ov; A[t]=ov; }
  __syncthreads();
  int wave=t>>6, lane=t&63;
  for(int r=wave; r<20; r+=8){
    const float* w=Wv+(size_t)r*325;
    float a=0.f;
    for(int c=lane;c<325;c+=64) a+=w[c]*A[c];
    for(int off=32;off>0;off>>=1) a+=__shfl_down(a,off,64);
    if(lane==0){
      float vv=a+bv[r];
      float rho=P[104];
      P[112+r]=rho*P[84+r]+(1.0f-rho)*vv;
    }
  }
}

// ------- K9: normalize rw/ww in-place + new_memory update -------
__global__ __launch_bounds__(256) void k_memupd(const float* __restrict__ M,
                         float* __restrict__ w_r, float* __restrict__ w_w,
                         const float* __restrict__ P, const double* __restrict__ Sd,
                         float* __restrict__ nm){
  int t=threadIdx.x, b=blockIdx.x;
  float er[20], af[20];
#pragma unroll
  for(int j=0;j<20;j++){ er[j]=P[64+j]; af[j]=P[112+j]; }
  float Zr=(float)Sd[0]+1e-16f, Zw=(float)Sd[1]+1e-16f;
  for(int p=0;p<4;p++){
    int i=b*1024+p*256+t;
    if(i<NN){
      float wrn=w_r[i]/Zr;
      float wwn=w_w[i]/Zw;
      w_r[i]=wrn; w_w[i]=wwn;
      const float4* row=(const float4*)(M+(size_t)i*WD);
      float4* dst=(float4*)(nm+(size_t)i*WD);
#pragma unroll
      for(int q=0;q<5;q++){
        float4 v=row[q];
        float4 o;
        o.x=v.x*(1.0f-wwn*er[4*q+0])+wwn*af[4*q+0];
        o.y=v.y*(1.0f-wwn*er[4*q+1])+wwn*af[4*q+1];
        o.z=v.z*(1.0f-wwn*er[4*q+2])+wwn*af[4*q+2];
        o.w=v.w*(1.0f-wwn*er[4*q+3])+wwn*af[4*q+3];
        dst[q]=o;
      }
    }
  }
}

extern "C" void kernel_launch(void* const* d_in, const int* in_sizes, int n_in,
                              void* d_out, int out_size, void* d_ws, size_t ws_size,
                              hipStream_t stream) {
  const float* X    =(const float*)d_in[0];
  const float* rwp  =(const float*)d_in[1];
  const float* wwp  =(const float*)d_in[2];
  const float* Mem  =(const float*)d_in[3];
  const float* rhd  =(const float*)d_in[4];
  const float* W1   =(const float*)d_in[5];
  const float* b1   =(const float*)d_in[6];
  const float* W2   =(const float*)d_in[7];
  const float* b2   =(const float*)d_in[8];
  const float* Wxi  =(const float*)d_in[9];
  const float* bxi  =(const float*)d_in[10];
  const float* Wz   =(const float*)d_in[11];
  const float* bz   =(const float*)d_in[12];
  const float* Wv   =(const float*)d_in[13];
  const float* bv   =(const float*)d_in[14];
  const float* aW1  =(const float*)d_in[15];
  const float* ab1  =(const float*)d_in[16];
  const float* aW2  =(const float*)d_in[17];
  const float* ab2  =(const float*)d_in[18];
  const float* aW3  =(const float*)d_in[19];
  const float* ab3  =(const float*)d_in[20];
  const float* aW4  =(const float*)d_in[21];
  const float* ab4  =(const float*)d_in[22];
  const float* mW1  =(const float*)d_in[23];
  const float* mb1  =(const float*)d_in[24];
  const float* mW2  =(const float*)d_in[25];
  const float* mb2  =(const float*)d_in[26];
  const float* mW3  =(const float*)d_in[27];
  const float* mb3  =(const float*)d_in[28];
  const float* mW4  =(const float*)d_in[29];
  const float* mb4  =(const float*)d_in[30];

  float* out = (float*)d_out;
  char* ws = (char*)d_ws;
  float*  P     = (float*) (ws + 0);        // 256 floats
  float4* pms   = (float4*)(ws + 4096);     // NB float4
  double* pZ    = (double*)(ws + 32768);    // NB*2 doubles
  double* pnrhT = (double*)(ws + 65536);    // 20*PST doubles (160KB)
  double* Sd    = (double*)(ws + 229376);   // [0]=Z_r [1]=Z_w
  float*  in40  = (float*) (ws + 229504);   // 40 floats
  float*  F     = (float*) (ws + 229760);   // MLP activations
  float *h1a=F,      *h1m=F+110;
  float *h2a=F+220,  *h2m=F+410;
  float *h3a=F+600,  *h3m=F+870;
  float *h4a=F+1140, *h4m=F+1465;

  // scores staged in the not-yet-written new_memory region of d_out
  float* score_r = out + NM_OFF;
  float* score_w = score_r + NN;
  float* w_r = out + RW_OFF;   // unnormalized until k_memupd normalizes in place
  float* w_w = out + WW_OFF;
  float* nm  = out + NM_OFF;

  k_head<<<1,128,0,stream>>>(X,W1,b1,W2,b2,Wxi,bxi,Wz,bz,P);
  k_scores<<<NB,256,0,stream>>>(Mem,P,score_r,score_w,pms);
  k_shift<<<NB,256,0,stream>>>(score_r,score_w,rwp,wwp,Mem,P,pms,w_r,w_w,pZ,pnrhT);
  k_nrh<<<20,256,0,stream>>>(pZ,pnrhT,rhd,in40,out,Sd);
  k_layer<<<56,256,0,stream>>>(aW1,ab1,mW1,mb1,in40,in40,h1a,h1m,110,40,28,1);
  k_layer<<<96,256,0,stream>>>(aW2,ab2,mW2,mb2,h1a,h1m,h2a,h2m,190,110,48,1);
  k_layer<<<136,256,0,stream>>>(aW3,ab3,mW3,mb3,h2a,h2m,h3a,h3m,270,190,68,1);
  k_layer<<<164,256,0,stream>>>(aW4,ab4,mW4,mb4,h3a,h3m,h4a,h4m,325,270,82,0);
  k_fin<<<1,512,0,stream>>>(h4a,h4m,Wv,bv,P,out);
  k_memupd<<<NB,256,0,stream>>>(Mem,w_r,w_w,P,Sd,nm);
}